// Round 4
// baseline (452.521 us; speedup 1.0000x reference)
//
#include <hip/hip_runtime.h>
#include <hip/hip_bf16.h>
#include <math.h>

#define T_TOK   131072
#define D_IN    2048
#define H_CH    260
#define NFRAG   17           // 17*16 = 272 padded N
#define KSTEPS  64           // 2048/32
#define STEP_BYTES  (NFRAG * 64 * 16)     // 17408 B per K-step of Wfrag
#define CHUNK_BYTES (2 * STEP_BYTES)      // 34816 B (2 K-steps)
#define NCHUNK  32

typedef __attribute__((ext_vector_type(8))) short bf16x8;
typedef __attribute__((ext_vector_type(4))) float f32x4;

__device__ inline short f2bf(float x) {
    __hip_bfloat16 h = __float2bfloat16(x);
    return __builtin_bit_cast(short, h);
}

// ---------------------------------------------------------------------------
// Prep: pack W_down [2048,260] fp32 -> MFMA-fragment-ready bf16 layout
// ---------------------------------------------------------------------------
__global__ void prep_wfrag(const float* __restrict__ W, __hip_bfloat16* __restrict__ Wf) {
    int g = blockIdx.x;                 // 0 .. KSTEPS*NFRAG-1
    int s = g / NFRAG, f = g % NFRAG;
    int lane = threadIdx.x;
    int k0 = s * 32 + (lane >> 4) * 8;
    int col = f * 16 + (lane & 15);
    short vals8[8];
#pragma unroll
    for (int j = 0; j < 8; j++) {
        float v = (col < H_CH) ? W[(size_t)(k0 + j) * H_CH + col] : 0.f;
        vals8[j] = f2bf(v);
    }
    *reinterpret_cast<bf16x8*>(reinterpret_cast<short*>(Wf) + ((size_t)g * 64 + lane) * 8) =
        *reinterpret_cast<bf16x8*>(vals8);
}

// ---------------------------------------------------------------------------
// Main GEMM, LDS-staged B (double-buffered) + chunk-level A register pipeline.
// Block = 256 threads (4 waves), M=128 rows (32/wave), full N=272.
// Per chunk (2 K-steps): stage B(c+1) + load A(c+1) regs, compute chunk c,
// one __syncthreads (vmcnt drain) per chunk.
// ---------------------------------------------------------------------------
__global__ __launch_bounds__(256, 2)
void gemm_act(const float* __restrict__ emb, const __hip_bfloat16* __restrict__ Wfrag,
              const float* __restrict__ b_down, const float* __restrict__ W_final,
              const float* __restrict__ b_final,
              float* __restrict__ attnL, __hip_bfloat16* __restrict__ vals,
              float* __restrict__ token_logits) {
    __shared__ __align__(16) char smem[2 * CHUNK_BYTES];   // 68 KB

    int wave = threadIdx.x >> 6;
    int lane = threadIdx.x & 63;
    int r0 = blockIdx.x * 128 + wave * 32;
    int row_in = lane & 15;
    int kbase = (lane >> 4) * 8;

    const char* gW = (const char*)Wfrag;

    auto stage_chunk = [&](int c, char* lbase) {
        const char* src = gW + (size_t)c * CHUNK_BYTES;
#pragma unroll
        for (int r = 0; r < 8; ++r) {
            int off = (r * 256 + wave * 64) * 16;
            __builtin_amdgcn_global_load_lds(
                (const __attribute__((address_space(1))) unsigned int*)(src + off + lane * 16),
                (__attribute__((address_space(3))) unsigned int*)(lbase + off), 16, 0, 0);
        }
        if (wave < 2) {   // tail: 34816 - 8*4096 = 2048 B
            int off = (8 * 256 + wave * 64) * 16;
            __builtin_amdgcn_global_load_lds(
                (const __attribute__((address_space(1))) unsigned int*)(src + off + lane * 16),
                (__attribute__((address_space(3))) unsigned int*)(lbase + off), 16, 0, 0);
        }
    };

    f32x4 acc0[NFRAG], acc1[NFRAG];
#pragma unroll
    for (int f = 0; f < NFRAG; f++) {
        acc0[f] = (f32x4){0.f, 0.f, 0.f, 0.f};
        acc1[f] = (f32x4){0.f, 0.f, 0.f, 0.f};
    }

    const float* ap0 = emb + (size_t)(r0 + row_in) * D_IN + kbase;
    const float* ap1 = ap0 + (size_t)16 * D_IN;

    f32x4 P0, P1, P2, P3, P4, P5, P6, P7;
    f32x4 Q0, Q1, Q2, Q3, Q4, Q5, Q6, Q7;

#define LOAD_A(R, off)                                            \
    R##0 = *reinterpret_cast<const f32x4*>(ap0 + (off));          \
    R##1 = *reinterpret_cast<const f32x4*>(ap0 + (off) + 4);      \
    R##2 = *reinterpret_cast<const f32x4*>(ap0 + (off) + 32);     \
    R##3 = *reinterpret_cast<const f32x4*>(ap0 + (off) + 36);     \
    R##4 = *reinterpret_cast<const f32x4*>(ap1 + (off));          \
    R##5 = *reinterpret_cast<const f32x4*>(ap1 + (off) + 4);      \
    R##6 = *reinterpret_cast<const f32x4*>(ap1 + (off) + 32);     \
    R##7 = *reinterpret_cast<const f32x4*>(ap1 + (off) + 36);

#define DO_STEP(AL0, AH0, AL1, AH1, BOFF)                                         \
    {                                                                             \
        bf16x8 af0, af1;                                                          \
        af0[0] = f2bf(AL0[0]); af0[1] = f2bf(AL0[1]);                             \
        af0[2] = f2bf(AL0[2]); af0[3] = f2bf(AL0[3]);                             \
        af0[4] = f2bf(AH0[0]); af0[5] = f2bf(AH0[1]);                             \
        af0[6] = f2bf(AH0[2]); af0[7] = f2bf(AH0[3]);                             \
        af1[0] = f2bf(AL1[0]); af1[1] = f2bf(AL1[1]);                             \
        af1[2] = f2bf(AL1[2]); af1[3] = f2bf(AL1[3]);                             \
        af1[4] = f2bf(AH1[0]); af1[5] = f2bf(AH1[1]);                             \
        af1[6] = f2bf(AH1[2]); af1[7] = f2bf(AH1[3]);                             \
        const char* bb = smem + (BOFF) + lane * 16;                               \
        _Pragma("unroll")                                                         \
        for (int f = 0; f < NFRAG; f++) {                                         \
            bf16x8 bfr = *reinterpret_cast<const bf16x8*>(bb + f * 1024);         \
            acc0[f] = __builtin_amdgcn_mfma_f32_16x16x32_bf16(af0, bfr, acc0[f], 0, 0, 0); \
            acc1[f] = __builtin_amdgcn_mfma_f32_16x16x32_bf16(af1, bfr, acc1[f], 0, 0, 0); \
        }                                                                         \
    }

#define DO_CHUNK(R, base)                                 \
    DO_STEP(R##0, R##1, R##4, R##5, (base));              \
    DO_STEP(R##2, R##3, R##6, R##7, (base) + STEP_BYTES);

    // prologue
    stage_chunk(0, smem);
    LOAD_A(P, 0)
    __syncthreads();   // chunk 0 B resident (A also drained)

    for (int i = 0; i < 16; ++i) {
        int c0 = 2 * i;
        // ---- chunk c0 (even -> buffer 0)
        stage_chunk(c0 + 1, smem + CHUNK_BYTES);
        LOAD_A(Q, (c0 + 1) * 64)
        DO_CHUNK(P, 0)
        __syncthreads();   // B(c0+1) + Q resident; buf0 free

        // ---- chunk c0+1 (odd -> buffer 1)
        if (i < 15) {
            stage_chunk(c0 + 2, smem);
            LOAD_A(P, (c0 + 2) * 64)
        }
        DO_CHUNK(Q, CHUNK_BYTES)
        __syncthreads();   // B(c0+2) + P resident; buf1 free
    }
#undef DO_CHUNK
#undef DO_STEP
#undef LOAD_A

    // Epilogue: bias, GELU (cols>=4), split stores, fused token-logit dot.
    int colbase = lane & 15;
    int rgroup = (lane >> 4) * 4;
    float tp0[4] = {0.f, 0.f, 0.f, 0.f};
    float tp1[4] = {0.f, 0.f, 0.f, 0.f};
#pragma unroll
    for (int f = 0; f < NFRAG; f++) {
        int n = f * 16 + colbase;
        float bias = (n < H_CH) ? b_down[n] : 0.f;
        float wf = (n >= 4 && n < H_CH) ? W_final[n - 4] : 0.f;
#pragma unroll
        for (int i = 0; i < 4; i++) {
            int row0 = r0 + rgroup + i;
            int row1 = row0 + 16;
            float v0 = acc0[f][i] + bias;
            float v1 = acc1[f][i] + bias;
            float a0 = (n < 4) ? v0 : 0.5f * v0 * (1.f + erff(v0 * 0.70710678118f));
            float a1 = (n < 4) ? v1 : 0.5f * v1 * (1.f + erff(v1 * 0.70710678118f));
            if (n < 4) {
                attnL[(size_t)row0 * 4 + n] = v0;
                attnL[(size_t)row1 * 4 + n] = v1;
            } else if (n < H_CH) {
                vals[(size_t)row0 * 256 + (n - 4)] = __float2bfloat16(a0);
                vals[(size_t)row1 * 256 + (n - 4)] = __float2bfloat16(a1);
            }
            tp0[i] += a0 * wf;
            tp1[i] += a1 * wf;
        }
    }
#pragma unroll
    for (int i = 0; i < 4; i++) {
        float v0 = tp0[i], v1 = tp1[i];
        v0 += __shfl_xor(v0, 1); v1 += __shfl_xor(v1, 1);
        v0 += __shfl_xor(v0, 2); v1 += __shfl_xor(v1, 2);
        v0 += __shfl_xor(v0, 4); v1 += __shfl_xor(v1, 4);
        v0 += __shfl_xor(v0, 8); v1 += __shfl_xor(v1, 8);
        if ((lane & 15) == 0) {
            token_logits[r0 + rgroup + i]      = v0 + b_final[0];
            token_logits[r0 + 16 + rgroup + i] = v1 + b_final[0];
        }
    }
}

// ---------------------------------------------------------------------------
// Problem pooling: 256 blocks (1 problem each), 256 threads.
// ---------------------------------------------------------------------------
__global__ __launch_bounds__(256)
void pool_problem(const float* __restrict__ attnL, const __hip_bfloat16* __restrict__ vals,
                  const int* __restrict__ labels,
                  const float* __restrict__ W_final, const float* __restrict__ b_final,
                  float* __restrict__ out_logits, float* __restrict__ out_labels) {
    __shared__ float w_lds[512 * 4];
    __shared__ float wred[4][4];
    __shared__ float psum[4];
    __shared__ int   lred[4];

    int p = blockIdx.x;
    int t = threadIdx.x;
    int lane = t & 63, wid = t >> 6;
    const float* abase = attnL + (size_t)p * 512 * 4;

    f32x4 v0 = *reinterpret_cast<const f32x4*>(abase + (size_t)t * 4);
    f32x4 v1 = *reinterpret_cast<const f32x4*>(abase + (size_t)(t + 256) * 4);

    float mh[4];
#pragma unroll
    for (int h = 0; h < 4; h++) mh[h] = fmaxf(v0[h], v1[h]);
#pragma unroll
    for (int h = 0; h < 4; h++)
        for (int mask = 1; mask < 64; mask <<= 1) mh[h] = fmaxf(mh[h], __shfl_xor(mh[h], mask));
    if (lane == 0) {
#pragma unroll
        for (int h = 0; h < 4; h++) wred[wid][h] = mh[h];
    }
    __syncthreads();
#pragma unroll
    for (int h = 0; h < 4; h++)
        mh[h] = fmaxf(fmaxf(wred[0][h], wred[1][h]), fmaxf(wred[2][h], wred[3][h]));
    __syncthreads();

    float Zh[4];
    f32x4 e0, e1;
#pragma unroll
    for (int h = 0; h < 4; h++) {
        e0[h] = __expf(v0[h] - mh[h]);
        e1[h] = __expf(v1[h] - mh[h]);
        Zh[h] = e0[h] + e1[h];
    }
    *reinterpret_cast<f32x4*>(&w_lds[t * 4]) = e0;
    *reinterpret_cast<f32x4*>(&w_lds[(t + 256) * 4]) = e1;
#pragma unroll
    for (int h = 0; h < 4; h++)
        for (int mask = 1; mask < 64; mask <<= 1) Zh[h] += __shfl_xor(Zh[h], mask);
    if (lane == 0) {
#pragma unroll
        for (int h = 0; h < 4; h++) wred[wid][h] = Zh[h];
    }
    __syncthreads();
#pragma unroll
    for (int h = 0; h < 4; h++) Zh[h] = wred[0][h] + wred[1][h] + wred[2][h] + wred[3][h];

    int h = t >> 6;
    const __hip_bfloat16* col = vals + (size_t)p * 512 * 256 + t;
    float pooled = 0.f;
#pragma unroll 8
    for (int s = 0; s < 512; s++)
        pooled += w_lds[s * 4 + h] * __bfloat162float(col[(size_t)s * 256]);
    float part = (pooled / Zh[h]) * W_final[t];
    for (int mask = 1; mask < 64; mask <<= 1) part += __shfl_xor(part, mask);
    if (lane == 0) psum[wid] = part;

    int lmin = min(labels[p * 512 + t], labels[p * 512 + t + 256]);
    for (int mask = 1; mask < 64; mask <<= 1) lmin = min(lmin, __shfl_xor(lmin, mask));
    if (lane == 0) lred[wid] = lmin;
    __syncthreads();
    if (t == 0) {
        out_logits[p] = psum[0] + psum[1] + psum[2] + psum[3] + b_final[0];
        out_labels[p] = (float)min(min(lred[0], lred[1]), min(lred[2], lred[3]));
    }
}

// ---------------------------------------------------------------------------
// Line pooling: one wave per line (16 tokens). Grid 2048 x 256 threads.
// ---------------------------------------------------------------------------
__global__ __launch_bounds__(256)
void pool_line(const float* __restrict__ attnL, const __hip_bfloat16* __restrict__ vals,
               const int* __restrict__ labels,
               const float* __restrict__ W_final, const float* __restrict__ b_final,
               float* __restrict__ out_logits, float* __restrict__ out_labels) {
    int wid = threadIdx.x >> 6, lane = threadIdx.x & 63;
    int line = blockIdx.x * 4 + wid;

    float x = attnL[(size_t)line * 64 + lane];
    float mm = x;
    mm = fmaxf(mm, __shfl_xor(mm, 4));
    mm = fmaxf(mm, __shfl_xor(mm, 8));
    mm = fmaxf(mm, __shfl_xor(mm, 16));
    mm = fmaxf(mm, __shfl_xor(mm, 32));
    float e = __expf(x - mm);
    float Z = e;
    Z += __shfl_xor(Z, 4);
    Z += __shfl_xor(Z, 8);
    Z += __shfl_xor(Z, 16);
    Z += __shfl_xor(Z, 32);
    float w = e / Z;

    const __hip_bfloat16* vbase = vals + (size_t)line * 16 * 256;
    float logit_part = 0.f;
#pragma unroll
    for (int j = 0; j < 4; j++) {
        float pooled = 0.f;
#pragma unroll
        for (int s = 0; s < 16; s++) {
            float ws = __shfl(w, s * 4 + j);
            pooled += ws * __bfloat162float(vbase[(size_t)s * 256 + j * 64 + lane]);
        }
        logit_part += pooled * W_final[j * 64 + lane];
    }
    for (int mask = 1; mask < 64; mask <<= 1) logit_part += __shfl_xor(logit_part, mask);

    int lab = (lane < 16) ? labels[line * 16 + lane] : 0x7fffffff;
    for (int mask = 1; mask < 64; mask <<= 1) lab = min(lab, __shfl_xor(lab, mask));

    if (lane == 0) {
        out_logits[line] = logit_part + b_final[0];
        out_labels[line] = (float)lab;
    }
}

// ---------------------------------------------------------------------------
extern "C" void kernel_launch(void* const* d_in, const int* in_sizes, int n_in,
                              void* d_out, int out_size, void* d_ws, size_t ws_size,
                              hipStream_t stream) {
    const float* emb     = (const float*)d_in[0];
    const float* W_down  = (const float*)d_in[1];
    const float* b_down  = (const float*)d_in[2];
    const float* W_final = (const float*)d_in[3];
    const float* b_final = (const float*)d_in[4];
    const int*   labels  = (const int*)d_in[5];

    float* out      = (float*)d_out;
    float* tok      = out;               // [131072]
    float* line_lg  = out + 131072;      // [8192]
    float* line_lb  = out + 139264;      // [8192]
    float* prob_lg  = out + 147456;      // [256]
    float* prob_lb  = out + 147712;      // [256]

    __hip_bfloat16* Wfrag = (__hip_bfloat16*)d_ws;                      // 1.1 MB
    float* attnL = (float*)((char*)d_ws + ((size_t)4 << 20));           // 2.1 MB
    __hip_bfloat16* vals = (__hip_bfloat16*)((char*)d_ws + ((size_t)8 << 20)); // 67 MB

    prep_wfrag<<<KSTEPS * NFRAG, 64, 0, stream>>>(W_down, Wfrag);
    gemm_act<<<T_TOK / 128, 256, 0, stream>>>(emb, Wfrag, b_down, W_final, b_final,
                                              attnL, vals, tok);
    pool_problem<<<256, 256, 0, stream>>>(attnL, vals, labels, W_final, b_final, prob_lg, prob_lb);
    pool_line<<<2048, 256, 0, stream>>>(attnL, vals, labels, W_final, b_final, line_lg, line_lb);
}

// Round 5
// 352.837 us; speedup vs baseline: 1.2825x; 1.2825x over previous
//
#include <hip/hip_runtime.h>
#include <hip/hip_bf16.h>
#include <math.h>

#define T_TOK   131072
#define D_IN    2048
#define H_CH    260
#define NFRAG   17           // 17*16 = 272 padded N
#define KSTEPS  64           // 2048/32
#define STEP_BYTES  (NFRAG * 64 * 16)     // 17408 B per K-step of Wfrag
#define CHUNK_BYTES (2 * STEP_BYTES)      // 34816 B (2 K-steps)
#define NCHUNK  32

typedef __attribute__((ext_vector_type(8))) short bf16x8;
typedef __attribute__((ext_vector_type(4))) float f32x4;

__device__ inline short f2bf(float x) {
    __hip_bfloat16 h = __float2bfloat16(x);
    return __builtin_bit_cast(short, h);
}

// ---------------------------------------------------------------------------
// Prep: pack W_down [2048,260] fp32 -> MFMA-fragment-ready bf16 layout
// ---------------------------------------------------------------------------
__global__ void prep_wfrag(const float* __restrict__ W, __hip_bfloat16* __restrict__ Wf) {
    int g = blockIdx.x;                 // 0 .. KSTEPS*NFRAG-1
    int s = g / NFRAG, f = g % NFRAG;
    int lane = threadIdx.x;
    int k0 = s * 32 + (lane >> 4) * 8;
    int col = f * 16 + (lane & 15);
    short vals8[8];
#pragma unroll
    for (int j = 0; j < 8; j++) {
        float v = (col < H_CH) ? W[(size_t)(k0 + j) * H_CH + col] : 0.f;
        vals8[j] = f2bf(v);
    }
    *reinterpret_cast<bf16x8*>(reinterpret_cast<short*>(Wf) + ((size_t)g * 64 + lane) * 8) =
        *reinterpret_cast<bf16x8*>(vals8);
}

// ---------------------------------------------------------------------------
// Main GEMM, LDS-staged B (double-buffered, global_load_lds width 16).
// Block = 512 threads (8 waves), M=128 rows -> 16 rows/wave, full N=272.
// acc = 17 f32x4 = 68 VGPR/wave -> target 4 waves/SIMD (2 blocks/CU).
// ---------------------------------------------------------------------------
__global__ __launch_bounds__(512, 4)
void gemm_act(const float* __restrict__ emb, const __hip_bfloat16* __restrict__ Wfrag,
              const float* __restrict__ b_down, const float* __restrict__ W_final,
              const float* __restrict__ b_final,
              float* __restrict__ attnL, __hip_bfloat16* __restrict__ vals,
              float* __restrict__ token_logits) {
    __shared__ __align__(16) char smem[2 * CHUNK_BYTES];   // 68 KB

    int wave = threadIdx.x >> 6;
    int lane = threadIdx.x & 63;
    int r0 = blockIdx.x * 128 + wave * 16;
    int row_in = lane & 15;
    int kbase = (lane >> 4) * 8;

    const char* gW = (const char*)Wfrag;

    // 34 x 1024B per chunk; waves 0..1 take 5 instrs, waves 2..7 take 4.
    auto stage_chunk = [&](int c, char* lbase) {
        const char* src = gW + (size_t)c * CHUNK_BYTES;
#pragma unroll
        for (int r = 0; r < 4; ++r) {
            int off = (r * 8 + wave) * 1024;
            __builtin_amdgcn_global_load_lds(
                (const __attribute__((address_space(1))) unsigned int*)(src + off + lane * 16),
                (__attribute__((address_space(3))) unsigned int*)(lbase + off), 16, 0, 0);
        }
        if (wave < 2) {
            int off = (32 + wave) * 1024;
            __builtin_amdgcn_global_load_lds(
                (const __attribute__((address_space(1))) unsigned int*)(src + off + lane * 16),
                (__attribute__((address_space(3))) unsigned int*)(lbase + off), 16, 0, 0);
        }
    };

    f32x4 acc[NFRAG];
#pragma unroll
    for (int f = 0; f < NFRAG; f++) acc[f] = (f32x4){0.f, 0.f, 0.f, 0.f};

    const float* aptr = emb + (size_t)(r0 + row_in) * D_IN + kbase;

    // prologue
    stage_chunk(0, smem);
    f32x4 cl = *reinterpret_cast<const f32x4*>(aptr);
    f32x4 ch = *reinterpret_cast<const f32x4*>(aptr + 4);
    f32x4 nl, nh;
    __syncthreads();   // chunk 0 resident

#define DO_STEP(AL, AH, BOFF)                                                     \
    {                                                                             \
        bf16x8 af;                                                                \
        af[0] = f2bf(AL[0]); af[1] = f2bf(AL[1]);                                 \
        af[2] = f2bf(AL[2]); af[3] = f2bf(AL[3]);                                 \
        af[4] = f2bf(AH[0]); af[5] = f2bf(AH[1]);                                 \
        af[6] = f2bf(AH[2]); af[7] = f2bf(AH[3]);                                 \
        const char* bb = smem + (BOFF) + lane * 16;                               \
        _Pragma("unroll")                                                         \
        for (int f = 0; f < NFRAG; f++) {                                         \
            bf16x8 bfr = *reinterpret_cast<const bf16x8*>(bb + f * 1024);         \
            acc[f] = __builtin_amdgcn_mfma_f32_16x16x32_bf16(af, bfr, acc[f], 0, 0, 0); \
        }                                                                         \
    }

    for (int c = 0; c < NCHUNK; ++c) {
        int base = (c & 1) * CHUNK_BYTES;
        if (c + 1 < NCHUNK) stage_chunk(c + 1, smem + ((c + 1) & 1) * CHUNK_BYTES);

        // step 2c: prefetch A(2c+1), compute
        int off1 = (2 * c + 1) * 32;
        nl = *reinterpret_cast<const f32x4*>(aptr + off1);
        nh = *reinterpret_cast<const f32x4*>(aptr + off1 + 4);
        DO_STEP(cl, ch, base)

        // step 2c+1: prefetch A(2c+2), compute
        int s2 = 2 * c + 2;
        int off2 = (s2 < KSTEPS ? s2 : 0) * 32;
        cl = *reinterpret_cast<const f32x4*>(aptr + off2);
        ch = *reinterpret_cast<const f32x4*>(aptr + off2 + 4);
        DO_STEP(nl, nh, base + STEP_BYTES)

        __syncthreads();   // next chunk resident; buf[c&1] free
    }
#undef DO_STEP

    // Epilogue: bias, GELU (cols>=4), split stores, fused token-logit dot.
    int colbase = lane & 15;
    int rgroup = (lane >> 4) * 4;
    float tp[4] = {0.f, 0.f, 0.f, 0.f};
#pragma unroll
    for (int f = 0; f < NFRAG; f++) {
        int n = f * 16 + colbase;
        float bias = (n < H_CH) ? b_down[n] : 0.f;
        float wf = (n >= 4 && n < H_CH) ? W_final[n - 4] : 0.f;
#pragma unroll
        for (int i = 0; i < 4; i++) {
            int row = r0 + rgroup + i;
            float v = acc[f][i] + bias;
            float a = (n < 4) ? v : 0.5f * v * (1.f + erff(v * 0.70710678118f));
            if (n < 4) {
                attnL[(size_t)row * 4 + n] = v;
            } else if (n < H_CH) {
                vals[(size_t)row * 256 + (n - 4)] = __float2bfloat16(a);
            }
            tp[i] += a * wf;
        }
    }
#pragma unroll
    for (int i = 0; i < 4; i++) {
        float v = tp[i];
        v += __shfl_xor(v, 1);
        v += __shfl_xor(v, 2);
        v += __shfl_xor(v, 4);
        v += __shfl_xor(v, 8);
        if ((lane & 15) == 0) token_logits[r0 + rgroup + i] = v + b_final[0];
    }
}

// ---------------------------------------------------------------------------
// Problem pooling: 256 blocks (1 problem each), 256 threads.
// ---------------------------------------------------------------------------
__global__ __launch_bounds__(256)
void pool_problem(const float* __restrict__ attnL, const __hip_bfloat16* __restrict__ vals,
                  const int* __restrict__ labels,
                  const float* __restrict__ W_final, const float* __restrict__ b_final,
                  float* __restrict__ out_logits, float* __restrict__ out_labels) {
    __shared__ float w_lds[512 * 4];
    __shared__ float wred[4][4];
    __shared__ float psum[4];
    __shared__ int   lred[4];

    int p = blockIdx.x;
    int t = threadIdx.x;
    int lane = t & 63, wid = t >> 6;
    const float* abase = attnL + (size_t)p * 512 * 4;

    f32x4 v0 = *reinterpret_cast<const f32x4*>(abase + (size_t)t * 4);
    f32x4 v1 = *reinterpret_cast<const f32x4*>(abase + (size_t)(t + 256) * 4);

    float mh[4];
#pragma unroll
    for (int h = 0; h < 4; h++) mh[h] = fmaxf(v0[h], v1[h]);
#pragma unroll
    for (int h = 0; h < 4; h++)
        for (int mask = 1; mask < 64; mask <<= 1) mh[h] = fmaxf(mh[h], __shfl_xor(mh[h], mask));
    if (lane == 0) {
#pragma unroll
        for (int h = 0; h < 4; h++) wred[wid][h] = mh[h];
    }
    __syncthreads();
#pragma unroll
    for (int h = 0; h < 4; h++)
        mh[h] = fmaxf(fmaxf(wred[0][h], wred[1][h]), fmaxf(wred[2][h], wred[3][h]));
    __syncthreads();

    float Zh[4];
    f32x4 e0, e1;
#pragma unroll
    for (int h = 0; h < 4; h++) {
        e0[h] = __expf(v0[h] - mh[h]);
        e1[h] = __expf(v1[h] - mh[h]);
        Zh[h] = e0[h] + e1[h];
    }
    *reinterpret_cast<f32x4*>(&w_lds[t * 4]) = e0;
    *reinterpret_cast<f32x4*>(&w_lds[(t + 256) * 4]) = e1;
#pragma unroll
    for (int h = 0; h < 4; h++)
        for (int mask = 1; mask < 64; mask <<= 1) Zh[h] += __shfl_xor(Zh[h], mask);
    if (lane == 0) {
#pragma unroll
        for (int h = 0; h < 4; h++) wred[wid][h] = Zh[h];
    }
    __syncthreads();
#pragma unroll
    for (int h = 0; h < 4; h++) Zh[h] = wred[0][h] + wred[1][h] + wred[2][h] + wred[3][h];

    int h = t >> 6;
    const __hip_bfloat16* col = vals + (size_t)p * 512 * 256 + t;
    float pooled = 0.f;
#pragma unroll 8
    for (int s = 0; s < 512; s++)
        pooled += w_lds[s * 4 + h] * __bfloat162float(col[(size_t)s * 256]);
    float part = (pooled / Zh[h]) * W_final[t];
    for (int mask = 1; mask < 64; mask <<= 1) part += __shfl_xor(part, mask);
    if (lane == 0) psum[wid] = part;

    int lmin = min(labels[p * 512 + t], labels[p * 512 + t + 256]);
    for (int mask = 1; mask < 64; mask <<= 1) lmin = min(lmin, __shfl_xor(lmin, mask));
    if (lane == 0) lred[wid] = lmin;
    __syncthreads();
    if (t == 0) {
        out_logits[p] = psum[0] + psum[1] + psum[2] + psum[3] + b_final[0];
        out_labels[p] = (float)min(min(lred[0], lred[1]), min(lred[2], lred[3]));
    }
}

// ---------------------------------------------------------------------------
// Line pooling: one wave per line (16 tokens). Grid 2048 x 256 threads.
// ---------------------------------------------------------------------------
__global__ __launch_bounds__(256)
void pool_line(const float* __restrict__ attnL, const __hip_bfloat16* __restrict__ vals,
               const int* __restrict__ labels,
               const float* __restrict__ W_final, const float* __restrict__ b_final,
               float* __restrict__ out_logits, float* __restrict__ out_labels) {
    int wid = threadIdx.x >> 6, lane = threadIdx.x & 63;
    int line = blockIdx.x * 4 + wid;

    float x = attnL[(size_t)line * 64 + lane];
    float mm = x;
    mm = fmaxf(mm, __shfl_xor(mm, 4));
    mm = fmaxf(mm, __shfl_xor(mm, 8));
    mm = fmaxf(mm, __shfl_xor(mm, 16));
    mm = fmaxf(mm, __shfl_xor(mm, 32));
    float e = __expf(x - mm);
    float Z = e;
    Z += __shfl_xor(Z, 4);
    Z += __shfl_xor(Z, 8);
    Z += __shfl_xor(Z, 16);
    Z += __shfl_xor(Z, 32);
    float w = e / Z;

    const __hip_bfloat16* vbase = vals + (size_t)line * 16 * 256;
    float logit_part = 0.f;
#pragma unroll
    for (int j = 0; j < 4; j++) {
        float pooled = 0.f;
#pragma unroll
        for (int s = 0; s < 16; s++) {
            float ws = __shfl(w, s * 4 + j);
            pooled += ws * __bfloat162float(vbase[(size_t)s * 256 + j * 64 + lane]);
        }
        logit_part += pooled * W_final[j * 64 + lane];
    }
    for (int mask = 1; mask < 64; mask <<= 1) logit_part += __shfl_xor(logit_part, mask);

    int lab = (lane < 16) ? labels[line * 16 + lane] : 0x7fffffff;
    for (int mask = 1; mask < 64; mask <<= 1) lab = min(lab, __shfl_xor(lab, mask));

    if (lane == 0) {
        out_logits[line] = logit_part + b_final[0];
        out_labels[line] = (float)lab;
    }
}

// ---------------------------------------------------------------------------
extern "C" void kernel_launch(void* const* d_in, const int* in_sizes, int n_in,
                              void* d_out, int out_size, void* d_ws, size_t ws_size,
                              hipStream_t stream) {
    const float* emb     = (const float*)d_in[0];
    const float* W_down  = (const float*)d_in[1];
    const float* b_down  = (const float*)d_in[2];
    const float* W_final = (const float*)d_in[3];
    const float* b_final = (const float*)d_in[4];
    const int*   labels  = (const int*)d_in[5];

    float* out      = (float*)d_out;
    float* tok      = out;               // [131072]
    float* line_lg  = out + 131072;      // [8192]
    float* line_lb  = out + 139264;      // [8192]
    float* prob_lg  = out + 147456;      // [256]
    float* prob_lb  = out + 147712;      // [256]

    __hip_bfloat16* Wfrag = (__hip_bfloat16*)d_ws;                      // 1.1 MB
    float* attnL = (float*)((char*)d_ws + ((size_t)4 << 20));           // 2.1 MB
    __hip_bfloat16* vals = (__hip_bfloat16*)((char*)d_ws + ((size_t)8 << 20)); // 67 MB

    prep_wfrag<<<KSTEPS * NFRAG, 64, 0, stream>>>(W_down, Wfrag);
    gemm_act<<<T_TOK / 128, 512, 0, stream>>>(emb, Wfrag, b_down, W_final, b_final,
                                              attnL, vals, tok);
    pool_problem<<<256, 256, 0, stream>>>(attnL, vals, labels, W_final, b_final, prob_lg, prob_lb);
    pool_line<<<2048, 256, 0, stream>>>(attnL, vals, labels, W_final, b_final, line_lg, line_lb);
}